// Round 13
// baseline (18.830 us; speedup 1.0000x reference)
//
#include <hip/hip_runtime.h>
#include <stdint.h>

#define H_MAX 8
#define NT 4096            // parallel window (freeze <= NT proven: r10-r12 absmax ~0.01)
#define K2T 1024           // threads per block (uniform)
#define NW 16              // waves in scan block
#define NRB 16             // producer (RNG) blocks
#define RSTEPS 256         // steps per producer block
#define MAGIC 0x5EED5EEDu  // != 0xAAAAAAAA poison, != 0 reset

__host__ __device__ __forceinline__ uint32_t rotl32(uint32_t v, int d) {
  return (v << d) | (v >> (32 - d));
}

// JAX threefry2x32 (jax/_src/prng.py), 20 rounds, key-injection schedule.
__host__ __device__ __forceinline__ void tf2x32(uint32_t k0, uint32_t k1,
                                                uint32_t x0, uint32_t x1,
                                                uint32_t& o0, uint32_t& o1) {
  const uint32_t ks2 = k0 ^ k1 ^ 0x1BD11BDAu;
#define TFR(d) { x0 += x1; x1 = rotl32(x1, d); x1 ^= x0; }
  x0 += k0; x1 += k1;
  TFR(13) TFR(15) TFR(26) TFR(6)
  x0 += k1;  x1 += ks2 + 1u;
  TFR(17) TFR(29) TFR(16) TFR(24)
  x0 += ks2; x1 += k0 + 2u;
  TFR(13) TFR(15) TFR(26) TFR(6)
  x0 += k0;  x1 += k1 + 3u;
  TFR(17) TFR(29) TFR(16) TFR(24)
  x0 += k1;  x1 += ks2 + 4u;
  TFR(13) TFR(15) TFR(26) TFR(6)
  x0 += ks2; x1 += k0 + 5u;
#undef TFR
  o0 = x0; o1 = x1;
}

__device__ __forceinline__ float u01f(uint32_t bits) {
  return __uint_as_float((bits >> 9) | 0x3f800000u) - 1.0f;
}

// Partitionable threefry random_bits (32-bit): bits1 ^ bits2 of block (0,i).
__device__ __forceinline__ uint32_t pbits32(uint32_t k0, uint32_t k1, uint32_t i) {
  uint32_t o0, o1;
  tf2x32(k0, k1, 0u, i, o0, o1);
  return o0 ^ o1;
}

// Single fused launch, 17 blocks x 1024.
// Blocks 1..16 (producers): zero-fill out (float4); 256 threads each compute
//   one step's RNG {a, c, E', u4} (validated collapse r6-r12: outer step is
//   x = fma(a,x,c), a = u1*swv/vw0, c = (Z+sbv)/vw0, E' = E/c_const; inner =
//   identity, encoded in consumer) into pre[] (transposed: slot =
//   (t&3)*K2T + (t>>2), coalesced consumer loads); then threadfence +
//   flag[b] = MAGIC (device-scope handshake per G16).
// Block 0 (consumer): preamble overlaps producers; lanes 0..15 spin on flags;
//   then the r12-validated parallel reconstruction: f64 affine scan for x,
//   f32 rcp for inc = E'/X, f32 prefix sum for pos, prefix count for j;
//   ta[j] = pos before inner step j; out[j-2] = ta[j] - ta[j-1]. Resets
//   flags to 0 after loads (graph-replay determinism). Post-freeze tail
//   (A saturated -> inc -> 0) matches ref's frozen pos exactly (zeros).
__global__ __launch_bounds__(K2T, 1) void gaps_fused(const float* __restrict__ w,
                                                     const float* __restrict__ bb,
                                                     const float* __restrict__ vv,
                                                     float4* __restrict__ pre,
                                                     uint32_t* __restrict__ flagsv,
                                                     float* __restrict__ out,
                                                     int k, int K2, int B, int H,
                                                     uint32_t sk0, uint32_t sk1,
                                                     uint32_t z0bits) {
  const int tid = threadIdx.x;

  // ---- shared constants (cheap; all blocks) ----
  float wf[H_MAX], bf[H_MAX], vf[H_MAX];
  for (int h = 0; h < H; ++h) {
    wf[h] = w[h];
    vf[h] = vv[h];
    bf[h] = (h == 0) ? 0.0f : bb[h - 1];
  }
  float sbv = 0.0f, swv = 0.0f;
  for (int h = 0; h < H; ++h) { sbv += bf[h] * vf[h]; swv += wf[h] * vf[h]; }
  const float ivw  = 1.0f / (vf[0] * wf[0]);
  const float GAIN = swv * ivw;
  const float C_F  = (float)(0.0001 + 1e-05);
  const float P_F  = (float)(0.0001 / (0.0001 + 1e-05));
  const float RCF  = 1.0f / C_F;
  const float INF  = __builtin_inff();

  if (blockIdx.x > 0) {
    // ================= producer =================
    const int b = blockIdx.x - 1;
    // float4 zero-fill of out (16 blocks x 1024 threads cover k/4 slots)
    const int gtid = b * K2T + tid;
    for (int i4 = gtid; i4 * 4 + 3 < k; i4 += NRB * K2T)
      ((float4*)out)[i4] = make_float4(0.0f, 0.0f, 0.0f, 0.0f);
    if (tid < RSTEPS) {
      const int t = b * RSTEPS + tid;
      uint32_t a0, a1;
      tf2x32(sk0, sk1, 0u, (uint32_t)t, a0, a1);    // keys[t] = block(key,(0,t))
      float u1 = u01f(pbits32(a0, a1, 0u));
      float Z  = -logf(u01f(pbits32(a0, a1, 1u)));  // -log(u2)
      float E  = -logf(u01f(pbits32(a0, a1, 2u)));  // -log(u3)
      float u4 = u01f(pbits32(a0, a1, 3u));
      int slot = (t & 3) * K2T + (t >> 2);
      pre[slot] = make_float4(u1 * GAIN, (Z + sbv) * ivw, E * RCF, u4);
    }
    __threadfence();                 // device-scope: writes visible before flag
    __syncthreads();
    if (tid == 0) atomicExch(&flagsv[b], MAGIC);
    return;
  }

  // ================= consumer (block 0) =================
  __shared__ double Aw[NW], Cw[NW];
  __shared__ float  Sw[NW];
  __shared__ int    Fw[NW];
  __shared__ float  sh_u4[K2T];
  __shared__ float  ta[NT];
  __shared__ double finX;
  __shared__ float  finP;
  __shared__ int    jfin;

  const int lane = tid & 63;
  const int wid  = tid >> 6;

  // preamble overlapping producers
  float z0  = -logf(u01f(z0bits));
  float x0f = (z0 + sbv) * ivw;          // inverse(z0), gate=1

  // ---- wait for all producers (device-scope handshake) ----
  if (tid < NRB) {
    while (atomicAdd(&flagsv[tid], 0u) != MAGIC) __builtin_amdgcn_s_sleep(2);
    __threadfence();                     // acquire: see producers' pre[] writes
  }
  __syncthreads();

  // ---- coalesced loads: r[i] = step tid*4+i ----
  float4 r0 = pre[0 * K2T + tid];
  float4 r1 = pre[1 * K2T + tid];
  float4 r2 = pre[2 * K2T + tid];
  float4 r3 = pre[3 * K2T + tid];

  // ---- neighbor shift for flag[4*tid]: u4 of step 4*tid-1 = r3.w of tid-1 ----
  sh_u4[tid] = r3.w;
  __syncthreads();                       // also drains the pre loads (vmcnt 0)
  if (tid < NRB) atomicExch(&flagsv[tid], 0u);   // reset for next graph replay
  float u4m1 = (tid == 0) ? 2.0f : sh_u4[tid - 1];   // 2.0 > p -> step 0 outer
  bool fl0 = (u4m1 < P_F);
  bool fl1 = (r0.w < P_F);
  bool fl2 = (r1.w < P_F);
  bool fl3 = (r2.w < P_F);
  // identity-encode inner steps (a,c) = (1,0)
  double a0d = fl0 ? 1.0 : (double)r0.x, c0d = fl0 ? 0.0 : (double)r0.y;
  double a1d = fl1 ? 1.0 : (double)r1.x, c1d = fl1 ? 0.0 : (double)r1.y;
  double a2d = fl2 ? 1.0 : (double)r2.x, c2d = fl2 ? 0.0 : (double)r2.y;
  double a3d = fl3 ? 1.0 : (double)r3.x, c3d = fl3 ? 0.0 : (double)r3.y;

  // ---- scan 1: affine (A,C), f64, inclusive two-level ----
  double A = 1.0, C = 0.0;
  C = a0d * C + c0d;  A = a0d * A;
  C = a1d * C + c1d;  A = a1d * A;
  C = a2d * C + c2d;  A = a2d * A;
  C = a3d * C + c3d;  A = a3d * A;
  for (int d = 1; d < 64; d <<= 1) {
    double Ap = __shfl_up(A, d);
    double Cp = __shfl_up(C, d);
    if (lane >= d) { C = A * Cp + C; A = A * Ap; }
  }
  if (lane == 63) { Aw[wid] = A; Cw[wid] = C; }
  __syncthreads();
  double Awp = 1.0, Cwp = 0.0;           // exclusive wave prefix (<=15 iters)
  for (int q = 0; q < wid; ++q) {
    double Aq = Aw[q], Cq = Cw[q];
    Cwp = Aq * Cwp + Cq;
    Awp = Aq * Awp;
  }
  double Aex = __shfl_up(A, 1), Cex = __shfl_up(C, 1);
  if (lane == 0) { Aex = 1.0; Cex = 0.0; }
  double Ag = Aex * Awp;                 // global exclusive prefix
  double Cg = Aex * Cwp + Cex;

  // ---- walk owned steps: X f64, inc f32 via rcp ----
  double X = Ag * (double)x0f + Cg;
  float inc0, inc1, inc2, inc3;
  X = a0d * X + c0d;  inc0 = r0.z * __builtin_amdgcn_rcpf((float)X);
  X = a1d * X + c1d;  inc1 = r1.z * __builtin_amdgcn_rcpf((float)X);
  X = a2d * X + c2d;  inc2 = r2.z * __builtin_amdgcn_rcpf((float)X);
  X = a3d * X + c3d;  inc3 = r3.z * __builtin_amdgcn_rcpf((float)X);
  float Sl = inc0 + inc1 + inc2 + inc3;
  int Fl = (fl0 ? 1 : 0) + (fl1 ? 1 : 0) + (fl2 ? 1 : 0) + (fl3 ? 1 : 0);

  // ---- scan 2: (sum inc f32, count flags) exclusive two-level ----
  float S = Sl; int F = Fl;
  for (int d = 1; d < 64; d <<= 1) {
    float Sp = __shfl_up(S, d);
    int   Fp = __shfl_up(F, d);
    if (lane >= d) { S += Sp; F += Fp; }
  }
  if (lane == 63) { Sw[wid] = S; Fw[wid] = F; }
  __syncthreads();
  float Swp = 0.0f; int Fwp = 0;
  for (int q = 0; q < wid; ++q) { Swp += Sw[q]; Fwp += Fw[q]; }
  float Sex = __shfl_up(S, 1); int Fex = __shfl_up(F, 1);
  if (lane == 0) { Sex = 0.0f; Fex = 0; }
  float P0 = Swp + Sex;                  // pos before first owned step
  int   J0 = Fwp + Fex;                  // j before first owned step

  // ---- emit ta[j] = pos before each inner step ----
  {
    float P = P0; int J = J0;
    if (fl0) { if (J < NT) ta[J] = P; ++J; }  P += inc0;
    if (fl1) { if (J < NT) ta[J] = P; ++J; }  P += inc1;
    if (fl2) { if (J < NT) ta[J] = P; ++J; }  P += inc2;
    if (fl3) { if (J < NT) ta[J] = P; ++J; }  P += inc3;
    if (tid == K2T - 1) { finX = X; finP = P; jfin = J; }
  }
  __syncthreads();

  // ---- emit gaps: out[j-2] = ta[j] - ta[j-1] ----
  {
    int J = J0;
    if (fl0) { if (J >= 2 && J < NT && (J - 2) < k) out[J - 2] = ta[J] - ta[J - 1]; ++J; }
    if (fl1) { if (J >= 2 && J < NT && (J - 2) < k) out[J - 2] = ta[J] - ta[J - 1]; ++J; }
    if (fl2) { if (J >= 2 && J < NT && (J - 2) < k) out[J - 2] = ta[J] - ta[J - 1]; ++J; }
    if (fl3) { if (J >= 2 && J < NT && (J - 2) < k) out[J - 2] = ta[J] - ta[J - 1]; ++J; }
  }

  // ---- defensive serial fallback (never taken: freeze <= NT proven) ----
  double Xf = finX;
  if (Xf >= 1e30) return;     // past this, all remaining ref gaps are 0
  if (tid >= 64) return;
  {
    float x = (float)Xf;
    float rcx = __builtin_amdgcn_rcpf(x);
    float pos = finP;
    int j = jfin;
    float pos_prev = (j >= 1 && j <= NT) ? ta[j - 1] : 0.0f;
    bool inner = (sh_u4[K2T - 1] < P_F) && (j < K2);   // u4[NT-1]
    bool done = false;
    for (int base = NT; base < B && !done; base += 64) {
      int t = base + lane;
      if (t >= B) t = B - 1;
      uint32_t a0, a1;
      tf2x32(sk0, sk1, 0u, (uint32_t)t, a0, a1);
      float aa = u01f(pbits32(a0, a1, 0u)) * GAIN;
      float cc = (-logf(u01f(pbits32(a0, a1, 1u))) + sbv) * ivw;
      float EE = -logf(u01f(pbits32(a0, a1, 2u))) * RCF;
      float u4 = u01f(pbits32(a0, a1, 3u));
      int lim = (B - base) < 64 ? (B - base) : 64;
      for (int s = 0; s < lim; ++s) {
        float Af = __shfl(aa, s);
        float Cf = __shfl(cc, s);
        float Ef = __shfl(EE, s);
        float U4 = __shfl(u4, s);
        if (inner) {
          if (j >= 2 && (j - 2) < k) out[j - 2] = pos - pos_prev;
          pos_prev = pos; ++j;
        } else {
          x = __builtin_fmaf(Af, x, Cf);
          rcx = __builtin_amdgcn_rcpf(x);
        }
        pos = __builtin_fmaf(Ef, rcx, pos);
        inner = (U4 < P_F) && (j < K2);
        if (x == INF || j >= K2) {
          if (x == INF && j >= 2 && (j - 2) < k) out[j - 2] = pos - pos_prev;
          done = true; break;
        }
      }
    }
    if (!done && j >= 2 && (j - 2) < k) out[j - 2] = 0.0f - pos_prev;
  }
}

extern "C" void kernel_launch(void* const* d_in, const int* in_sizes, int n_in,
                              void* d_out, int out_size, void* d_ws, size_t ws_size,
                              hipStream_t stream) {
  const float* w = (const float*)d_in[0];   // (1,H)
  const float* b = (const float*)d_in[1];   // (H-1,)
  const float* v = (const float*)d_in[2];   // (H,1)
  (void)n_in; (void)ws_size;
  const int H  = in_sizes[0];
  const int k  = out_size;                  // 16384
  const int K2 = k + 2;
  const int B  = 2 * K2 + 256;              // 33028

  // Partitionable split: key(1234) = (0,1234);
  // split(key,2)[i] = full block (o0,o1) of tf(key, 0, i).
  uint32_t ka0, ka1, kb0, kb1;
  tf2x32(0u, 1234u, 0u, 0u, ka0, ka1);      // keys[0] -> carried key
  tf2x32(0u, 1234u, 0u, 1u, kb0, kb1);      // keys[1] -> k0 (for z0)
  uint32_t zb0, zb1;
  tf2x32(kb0, kb1, 0u, 0u, zb0, zb1);
  const uint32_t z0bits = zb0 ^ zb1;        // scalar uniform bits: o0^o1

  float4*   pre   = (float4*)d_ws;                       // NT*16 B = 64 KB
  uint32_t* flags = (uint32_t*)((char*)d_ws + NT * 16);  // 16 u32 handshake

  gaps_fused<<<dim3(NRB + 1), K2T, 0, stream>>>(w, b, v, pre, flags,
                                                (float*)d_out,
                                                k, K2, B, H, ka0, ka1, z0bits);
}

// Round 14
// 17.592 us; speedup vs baseline: 1.0704x; 1.0704x over previous
//
#include <hip/hip_runtime.h>
#include <stdint.h>

#define H_MAX 8
#define NT 4096            // parallel window (freeze ~2700 steps; 1.5x margin)
#define K1T 256
#define K1B (NT / K1T)     // 16 blocks
#define K2T 1024
#define NW 16              // waves in K2

__host__ __device__ __forceinline__ uint32_t rotl32(uint32_t v, int d) {
  return (v << d) | (v >> (32 - d));
}

// JAX threefry2x32 (jax/_src/prng.py), 20 rounds, key-injection schedule.
__host__ __device__ __forceinline__ void tf2x32(uint32_t k0, uint32_t k1,
                                                uint32_t x0, uint32_t x1,
                                                uint32_t& o0, uint32_t& o1) {
  const uint32_t ks2 = k0 ^ k1 ^ 0x1BD11BDAu;
#define TFR(d) { x0 += x1; x1 = rotl32(x1, d); x1 ^= x0; }
  x0 += k0; x1 += k1;
  TFR(13) TFR(15) TFR(26) TFR(6)
  x0 += k1;  x1 += ks2 + 1u;
  TFR(17) TFR(29) TFR(16) TFR(24)
  x0 += ks2; x1 += k0 + 2u;
  TFR(13) TFR(15) TFR(26) TFR(6)
  x0 += k0;  x1 += k1 + 3u;
  TFR(17) TFR(29) TFR(16) TFR(24)
  x0 += k1;  x1 += ks2 + 4u;
  TFR(13) TFR(15) TFR(26) TFR(6)
  x0 += ks2; x1 += k0 + 5u;
#undef TFR
  o0 = x0; o1 = x1;
}

__device__ __forceinline__ float u01f(uint32_t bits) {
  return __uint_as_float((bits >> 9) | 0x3f800000u) - 1.0f;
}

// Partitionable threefry random_bits (32-bit): bits1 ^ bits2 of block (0,i).
__device__ __forceinline__ uint32_t pbits32(uint32_t k0, uint32_t k1, uint32_t i) {
  uint32_t o0, o1;
  tf2x32(k0, k1, 0u, i, o0, o1);
  return o0 ^ o1;
}

// K1: grid-parallel RNG + coefficient encode (validated collapse, r6-r13):
//   outer step: x = fma(a,x,c), a = u1*swv/vw0, c = (Z+sbv)/vw0
//   inner step: identity -> encoded (a,c) = (1,0); .w = flag
//   flag[t] = (u4[t-1] < p), flag[0]=0.  E' = E/c_const.
// Transposed layout: step t -> slot (t&3)*K2T + (t>>2), so K2's i-th load
// is perfectly coalesced. Slot NT holds raw u4[NT-1] for the fallback.
// Also zero-fills out (post-freeze tail exactly 0; resets graph replays).
__global__ __launch_bounds__(K1T) void rng_kernel(const float* __restrict__ w,
                                                  const float* __restrict__ bb,
                                                  const float* __restrict__ vv,
                                                  float4* __restrict__ pre,
                                                  float* __restrict__ out,
                                                  int k, int H,
                                                  uint32_t sk0, uint32_t sk1) {
  const int t = blockIdx.x * K1T + threadIdx.x;

  float wf[H_MAX], bf[H_MAX], vf[H_MAX];
  for (int h = 0; h < H; ++h) {
    wf[h] = w[h];
    vf[h] = vv[h];
    bf[h] = (h == 0) ? 0.0f : bb[h - 1];
  }
  float sbv = 0.0f, swv = 0.0f;
  for (int h = 0; h < H; ++h) { sbv += bf[h] * vf[h]; swv += wf[h] * vf[h]; }
  const float ivw  = 1.0f / (vf[0] * wf[0]);
  const float GAIN = swv * ivw;
  const float C_F  = (float)(0.0001 + 1e-05);
  const float P_F  = (float)(0.0001 / (0.0001 + 1e-05));
  const float RCF  = 1.0f / C_F;

  for (int i = t; i < k; i += NT) out[i] = 0.0f;

  uint32_t a0, a1;
  tf2x32(sk0, sk1, 0u, (uint32_t)t, a0, a1);        // keys[t] = block(key,(0,t))
  float u1 = u01f(pbits32(a0, a1, 0u));
  float Z  = -logf(u01f(pbits32(a0, a1, 1u)));      // -log(u2)
  float E  = -logf(u01f(pbits32(a0, a1, 2u)));      // -log(u3)
  bool f = false;
  if (t > 0) {                                      // flag = u4[t-1] < p
    uint32_t p0, p1;
    tf2x32(sk0, sk1, 0u, (uint32_t)(t - 1), p0, p1);
    f = u01f(pbits32(p0, p1, 3u)) < P_F;
  }
  int slot = (t & 3) * K2T + (t >> 2);
  pre[slot] = make_float4(f ? 1.0f : u1 * GAIN,
                          f ? 0.0f : (Z + sbv) * ivw,
                          E * RCF, f ? 1.0f : 0.0f);
  if (t == NT - 1) {                                // u4[NT-1] for fallback
    float u4 = u01f(pbits32(a0, a1, 3u));
    pre[NT] = make_float4(u4, 0.0f, 0.0f, 0.0f);
  }
}

// K2: the parallel reconstruction (r10-r13-validated structure).
// x: affine f64 scan (composed coeffs ~1e98 in-window, no overflow; beyond
// freeze A saturates -> inc -> 0 = ref's frozen tail). pos: prefix sum of
// E'/X. j: prefix count of flags. ta[j] = pos before inner step j;
// out[j-2] = ta[j] - ta[j-1].
__global__ __launch_bounds__(K2T, 1) void scan_kernel(const float* __restrict__ w,
                                                      const float* __restrict__ bb,
                                                      const float* __restrict__ vv,
                                                      const float4* __restrict__ pre,
                                                      float* __restrict__ out,
                                                      int k, int K2, int B, int H,
                                                      uint32_t sk0, uint32_t sk1,
                                                      uint32_t z0bits) {
  __shared__ double Aw[NW], Cw[NW], Sw[NW];
  __shared__ int    Fw[NW];
  __shared__ float  ta[NT];
  __shared__ double fin[2];    // X_final, P_total
  __shared__ int    jfin;

  const int tid  = threadIdx.x;
  const int lane = tid & 63;
  const int wid  = tid >> 6;

  float wf[H_MAX], bf[H_MAX], vf[H_MAX];
  for (int h = 0; h < H; ++h) {
    wf[h] = w[h];
    vf[h] = vv[h];
    bf[h] = (h == 0) ? 0.0f : bb[h - 1];
  }
  float sbv = 0.0f, swv = 0.0f;
  for (int h = 0; h < H; ++h) { sbv += bf[h] * vf[h]; swv += wf[h] * vf[h]; }
  const float ivw  = 1.0f / (vf[0] * wf[0]);
  const float GAIN = swv * ivw;
  const float C_F  = (float)(0.0001 + 1e-05);
  const float P_F  = (float)(0.0001 / (0.0001 + 1e-05));
  const float RCF  = 1.0f / C_F;
  const float INF  = __builtin_inff();

  // ---- coalesced loads: r[i] = step tid*4+i ----
  float4 r0 = pre[0 * K2T + tid];
  float4 r1 = pre[1 * K2T + tid];
  float4 r2 = pre[2 * K2T + tid];
  float4 r3 = pre[3 * K2T + tid];
  bool fl0 = (r0.w != 0.0f), fl1 = (r1.w != 0.0f),
       fl2 = (r2.w != 0.0f), fl3 = (r3.w != 0.0f);

  // ---- scan 1: affine (A,C), f64, inclusive two-level ----
  double A = 1.0, C = 0.0;     // local compose (inner already encoded (1,0))
  C = (double)r0.x * C + (double)r0.y;  A = (double)r0.x * A;
  C = (double)r1.x * C + (double)r1.y;  A = (double)r1.x * A;
  C = (double)r2.x * C + (double)r2.y;  A = (double)r2.x * A;
  C = (double)r3.x * C + (double)r3.y;  A = (double)r3.x * A;
  for (int d = 1; d < 64; d <<= 1) {
    double Ap = __shfl_up(A, d);
    double Cp = __shfl_up(C, d);
    if (lane >= d) { C = A * Cp + C; A = A * Ap; }
  }
  if (lane == 63) { Aw[wid] = A; Cw[wid] = C; }
  __syncthreads();
  double Awp = 1.0, Cwp = 0.0;           // exclusive wave prefix (serial, 15)
  for (int q = 0; q < wid; ++q) {
    double Aq = Aw[q], Cq = Cw[q];
    Cwp = Aq * Cwp + Cq;
    Awp = Aq * Awp;
  }
  double Aex = __shfl_up(A, 1), Cex = __shfl_up(C, 1);
  if (lane == 0) { Aex = 1.0; Cex = 0.0; }
  double Ag = Aex * Awp;                 // global exclusive prefix
  double Cg = Aex * Cwp + Cex;

  // ---- walk owned steps: X per step, inc = E'/X ----
  float z0  = -logf(u01f(z0bits));
  float x0f = (z0 + sbv) * ivw;          // inverse(z0), gate=1
  double X = Ag * (double)x0f + Cg;
  double inc0, inc1, inc2, inc3;
  if (!fl0) X = (double)r0.x * X + (double)r0.y;  inc0 = (double)r0.z / X;
  if (!fl1) X = (double)r1.x * X + (double)r1.y;  inc1 = (double)r1.z / X;
  if (!fl2) X = (double)r2.x * X + (double)r2.y;  inc2 = (double)r2.z / X;
  if (!fl3) X = (double)r3.x * X + (double)r3.y;  inc3 = (double)r3.z / X;
  double Sl = inc0 + inc1 + inc2 + inc3;
  int Fl = (fl0 ? 1 : 0) + (fl1 ? 1 : 0) + (fl2 ? 1 : 0) + (fl3 ? 1 : 0);

  // ---- scan 2: (sum inc, count flags), exclusive two-level ----
  double S = Sl; int F = Fl;
  for (int d = 1; d < 64; d <<= 1) {
    double Sp = __shfl_up(S, d);
    int    Fp = __shfl_up(F, d);
    if (lane >= d) { S += Sp; F += Fp; }
  }
  if (lane == 63) { Sw[wid] = S; Fw[wid] = F; }
  __syncthreads();
  double Swp = 0.0; int Fwp = 0;
  for (int q = 0; q < wid; ++q) { Swp += Sw[q]; Fwp += Fw[q]; }
  double Sex = __shfl_up(S, 1); int Fex = __shfl_up(F, 1);
  if (lane == 0) { Sex = 0.0; Fex = 0; }
  double P0 = Swp + Sex;                 // pos before first owned step
  int    J0 = Fwp + Fex;                 // j before first owned step

  // ---- emit ta[j] = pos before each inner step ----
  {
    double P = P0; int J = J0;
    if (fl0) { if (J < NT) ta[J] = (float)P; ++J; }  P += inc0;
    if (fl1) { if (J < NT) ta[J] = (float)P; ++J; }  P += inc1;
    if (fl2) { if (J < NT) ta[J] = (float)P; ++J; }  P += inc2;
    if (fl3) { if (J < NT) ta[J] = (float)P; ++J; }  P += inc3;
    if (tid == K2T - 1) { fin[0] = X; fin[1] = P; jfin = J; }
  }
  __syncthreads();

  // ---- emit gaps: out[j-2] = ta[j] - ta[j-1] ----
  {
    int J = J0;
    if (fl0) { if (J >= 2 && J < NT && (J - 2) < k) out[J - 2] = ta[J] - ta[J - 1]; ++J; }
    if (fl1) { if (J >= 2 && J < NT && (J - 2) < k) out[J - 2] = ta[J] - ta[J - 1]; ++J; }
    if (fl2) { if (J >= 2 && J < NT && (J - 2) < k) out[J - 2] = ta[J] - ta[J - 1]; ++J; }
    if (fl3) { if (J >= 2 && J < NT && (J - 2) < k) out[J - 2] = ta[J] - ta[J - 1]; ++J; }
  }

  // ---- defensive serial fallback (never taken: freeze << NT) ----
  double Xf = fin[0];
  if (Xf >= 1e30) return;     // past this, all remaining ref gaps are 0
  if (tid >= 64) return;
  {
    float x = (float)Xf;
    float rcx = __builtin_amdgcn_rcpf(x);
    float pos = (float)fin[1];
    int j = jfin;
    float pos_prev = (j >= 1 && j <= NT) ? ta[j - 1] : 0.0f;
    bool inner = (pre[NT].x < P_F) && (j < K2);   // u4[NT-1]
    bool done = false;
    for (int base = NT; base < B && !done; base += 64) {
      int t = base + lane;
      if (t >= B) t = B - 1;
      uint32_t a0, a1;
      tf2x32(sk0, sk1, 0u, (uint32_t)t, a0, a1);
      float aa = u01f(pbits32(a0, a1, 0u)) * GAIN;
      float cc = (-logf(u01f(pbits32(a0, a1, 1u))) + sbv) * ivw;
      float EE = -logf(u01f(pbits32(a0, a1, 2u))) * RCF;
      float u4 = u01f(pbits32(a0, a1, 3u));
      int lim = (B - base) < 64 ? (B - base) : 64;
      for (int s = 0; s < lim; ++s) {
        float Af = __shfl(aa, s);
        float Cf = __shfl(cc, s);
        float Ef = __shfl(EE, s);
        float U4 = __shfl(u4, s);
        if (inner) {
          if (j >= 2 && (j - 2) < k) out[j - 2] = pos - pos_prev;
          pos_prev = pos; ++j;
        } else {
          x = __builtin_fmaf(Af, x, Cf);
          rcx = __builtin_amdgcn_rcpf(x);
        }
        pos = __builtin_fmaf(Ef, rcx, pos);
        inner = (U4 < P_F) && (j < K2);
        if (x == INF || j >= K2) {
          if (x == INF && j >= 2 && (j - 2) < k) out[j - 2] = pos - pos_prev;
          done = true; break;
        }
      }
    }
    if (!done && j >= 2 && (j - 2) < k) out[j - 2] = 0.0f - pos_prev;
  }
}

extern "C" void kernel_launch(void* const* d_in, const int* in_sizes, int n_in,
                              void* d_out, int out_size, void* d_ws, size_t ws_size,
                              hipStream_t stream) {
  const float* w = (const float*)d_in[0];   // (1,H)
  const float* b = (const float*)d_in[1];   // (H-1,)
  const float* v = (const float*)d_in[2];   // (H,1)
  (void)n_in; (void)ws_size;
  const int H  = in_sizes[0];
  const int k  = out_size;                  // 16384
  const int K2 = k + 2;
  const int B  = 2 * K2 + 256;              // 33028

  // Partitionable split: key(1234) = (0,1234);
  // split(key,2)[i] = full block (o0,o1) of tf(key, 0, i).
  uint32_t ka0, ka1, kb0, kb1;
  tf2x32(0u, 1234u, 0u, 0u, ka0, ka1);      // keys[0] -> carried key
  tf2x32(0u, 1234u, 0u, 1u, kb0, kb1);      // keys[1] -> k0 (for z0)
  uint32_t zb0, zb1;
  tf2x32(kb0, kb1, 0u, 0u, zb0, zb1);
  const uint32_t z0bits = zb0 ^ zb1;        // scalar uniform bits: o0^o1

  float4* pre = (float4*)d_ws;              // (NT+1)*16 B = 65.5 KB

  rng_kernel<<<dim3(K1B), K1T, 0, stream>>>(w, b, v, pre, (float*)d_out,
                                            k, H, ka0, ka1);
  scan_kernel<<<dim3(1), K2T, 0, stream>>>(w, b, v, pre, (float*)d_out,
                                           k, K2, B, H, ka0, ka1, z0bits);
}